// Round 3
// baseline (1311.002 us; speedup 1.0000x reference)
//
#include <hip/hip_runtime.h>

// ---------------------------------------------------------------------------
// EnterpriseGNN: 3-layer GCN on MI355X.
//   h1 = relu(GCNConv(x, W1, b1));  h2 = relu(GCNConv(h1, W2, b2));
//   out = h2 @ Wout + bout
// GCNConv(x,W,b)[i] = dinv[i] * ( sum_{e:dst=i} w_e * g[src_e] + g[i] ) + b
//   where g = dinv .* (x@W),  dinv = rsqrt(deg+1), deg = sum_{e:dst=i} w_e.
//
// R3: coarse bucketing (256 nodes/bucket, 391 buckets) replaces full CSR.
// Scattered fabric ops (~130us per edge-sized class) eliminated:
//   - hist: LDS histogram, <=512 global atomics/block
//   - scatter: per-(block,bucket) reservation -> coalesced ~168B runs
//   - aggregation: LDS f32 atomics per bucket (ds_add_f32, no write-through),
//     fused dinv/bias/relu epilogue.
// Remaining cost: random g[src] reads through L2/L3 (structural).
// ---------------------------------------------------------------------------

#define BLK 256
#define S_NODES 256        // nodes per bucket
#define MAXB 512           // max buckets -> supports N <= 131072
#define CHUNK 8192         // edges per partition block

typedef unsigned long long u64;
typedef unsigned int u32;

// ---------------- bucketed path ----------------

// per-bucket edge counts (LDS histogram, tiny global flush)
__global__ void bucket_count_kernel(const int* __restrict__ dst,
                                    int* __restrict__ gcnt, int E) {
    __shared__ int h[MAXB];
    for (int i = threadIdx.x; i < MAXB; i += BLK) h[i] = 0;
    __syncthreads();
    int stride = gridDim.x * blockDim.x;
    for (int e = blockIdx.x * blockDim.x + threadIdx.x; e < E; e += stride)
        atomicAdd(&h[dst[e] >> 8], 1);
    __syncthreads();
    for (int i = threadIdx.x; i < MAXB; i += BLK)
        if (h[i]) atomicAdd(&gcnt[i], h[i]);
}

// single block: exclusive scan of gcnt[B] -> gstart, gcur
__global__ void bucket_scan_kernel(const int* __restrict__ gcnt,
                                   int* __restrict__ gstart,
                                   int* __restrict__ gcur, int B) {
    __shared__ int s[MAXB];
    for (int i = threadIdx.x; i < B; i += BLK) s[i] = gcnt[i];
    __syncthreads();
    if (threadIdx.x == 0) {
        int run = 0;
        for (int i = 0; i < B; i++) { int v = s[i]; s[i] = run; run += v; }
    }
    __syncthreads();
    for (int i = threadIdx.x; i < B; i += BLK) { gstart[i] = s[i]; gcur[i] = s[i]; }
}

// partition edges into bucket regions; within-bucket order arbitrary.
// record: [w:32][dst_local:8][src:24]
__global__ void partition_kernel(const int* __restrict__ src,
                                 const int* __restrict__ dst,
                                 const float* __restrict__ w,
                                 int* __restrict__ gcur,
                                 u64* __restrict__ packed, int E) {
    __shared__ int lcnt[MAXB];
    __shared__ int lbase[MAXB];
    int e0 = blockIdx.x * CHUNK;
    int e1 = min(e0 + CHUNK, E);
    for (int i = threadIdx.x; i < MAXB; i += BLK) lcnt[i] = 0;
    __syncthreads();
    for (int e = e0 + threadIdx.x; e < e1; e += BLK)
        atomicAdd(&lcnt[dst[e] >> 8], 1);
    __syncthreads();
    // reserve contiguous global run per bucket for this block
    for (int b = threadIdx.x; b < MAXB; b += BLK) {
        int c = lcnt[b];
        lbase[b] = c ? atomicAdd(&gcur[b], c) : 0;
    }
    __syncthreads();
    for (int i = threadIdx.x; i < MAXB; i += BLK) lcnt[i] = 0;  // reuse as cursor
    __syncthreads();
    for (int e = e0 + threadIdx.x; e < e1; e += BLK) {
        int d = dst[e];
        int b = d >> 8;
        int pos = lbase[b] + atomicAdd(&lcnt[b], 1);
        u64 rec = ((u64)__float_as_uint(w[e]) << 32) |
                  ((u64)(u32)(d & 255) << 24) | (u32)src[e];
        packed[pos] = rec;
    }
}

// deg per node from bucketed records (LDS accumulation), dinv out
__global__ void bucket_deg_kernel(const u64* __restrict__ packed,
                                  const int* __restrict__ gstart,
                                  const int* __restrict__ gcnt,
                                  float* __restrict__ dinv, int N) {
    __shared__ float sacc[S_NODES];
    int b = blockIdx.x;
    int n0 = b << 8;
    for (int i = threadIdx.x; i < S_NODES; i += BLK) sacc[i] = 0.f;
    __syncthreads();
    int s = gstart[b], e = s + gcnt[b];
    for (int i = s + threadIdx.x; i < e; i += BLK) {
        u64 rec = packed[i];
        atomicAdd(&sacc[(int)((rec >> 24) & 255)],
                  __uint_as_float((u32)(rec >> 32)));
    }
    __syncthreads();
    for (int i = threadIdx.x; i < S_NODES; i += BLK) {
        int n = n0 + i;
        if (n < N) dinv[n] = rsqrtf(sacc[i] + 1.0f);
    }
}

// bucketed aggregation + fused GCN epilogue:
//   h[n][f] = relu( dinv[n] * (sum_e w_e * g[src_e][f] + g[n][f]) + bias[f] )
template <int F>
__global__ void bucket_agg_kernel(const u64* __restrict__ packed,
                                  const int* __restrict__ gstart,
                                  const int* __restrict__ gcnt,
                                  const float* __restrict__ g,
                                  const float* __restrict__ dinv,
                                  const float* __restrict__ bias,
                                  float* __restrict__ h, int N) {
    __shared__ float sacc[S_NODES * F];  // 32 KB (F=32) / 16 KB (F=16)
    const int NG = BLK / F;              // record groups per iteration
    int b = blockIdx.x;
    int n0 = b << 8;
    for (int i = threadIdx.x; i < S_NODES * F; i += BLK) sacc[i] = 0.f;
    __syncthreads();
    int s0 = gstart[b];
    int e0 = s0 + gcnt[b];
    int f = threadIdx.x & (F - 1);
    int grp = threadIdx.x / F;
    int i = s0 + grp;
    // 8-way unrolled: 8 independent L2/L3 gathers in flight per group
    for (; i + 7 * NG < e0; i += 8 * NG) {
        u64 r[8];
        float gv[8];
#pragma unroll
        for (int k = 0; k < 8; k++) r[k] = packed[i + k * NG];
#pragma unroll
        for (int k = 0; k < 8; k++)
            gv[k] = g[(size_t)(u32)(r[k] & 0xFFFFFF) * F + f];
#pragma unroll
        for (int k = 0; k < 8; k++)
            atomicAdd(&sacc[(int)((r[k] >> 24) & 255) * F + f],
                      __uint_as_float((u32)(r[k] >> 32)) * gv[k]);
    }
    for (; i < e0; i += NG) {
        u64 r = packed[i];
        float gv = g[(size_t)(u32)(r & 0xFFFFFF) * F + f];
        atomicAdd(&sacc[(int)((r >> 24) & 255) * F + f],
                  __uint_as_float((u32)(r >> 32)) * gv);
    }
    __syncthreads();
    for (int t = threadIdx.x; t < S_NODES * F; t += BLK) {
        int ln = t / F, ff = t & (F - 1);
        int n = n0 + ln;
        if (n < N)
            h[(size_t)n * F + ff] =
                fmaxf(dinv[n] * (sacc[t] + g[(size_t)n * F + ff]) + bias[ff], 0.f);
    }
}

// g1[i][j] = dinv[i] * sum_k x[i][k] * W1[k][j]   (128 -> 32)
__global__ void gemm1_kernel(const float* __restrict__ x,
                             const float* __restrict__ W1,
                             const float* __restrict__ dinv,
                             float* __restrict__ g1, int N) {
    __shared__ float sW[128 * 32];   // 16 KB
    __shared__ float sx[8][128];     // 4 KB
    const float4* W4 = (const float4*)W1;
    float4* sW4 = (float4*)sW;
    for (int i = threadIdx.x; i < 1024; i += BLK) sW4[i] = W4[i];
    int node0 = blockIdx.x * 8;
    {
        int r = threadIdx.x >> 5, c4 = threadIdx.x & 31;  // 8 rows x 32 float4
        int n = node0 + r;
        float4 v = make_float4(0.f, 0.f, 0.f, 0.f);
        if (n < N) v = *(const float4*)&x[(size_t)n * 128 + c4 * 4];
        *(float4*)&sx[r][c4 * 4] = v;
    }
    __syncthreads();
    int local = threadIdx.x >> 5;     // node within block (0..7)
    int j = threadIdx.x & 31;         // output feature
    int n = node0 + local;
    if (n < N) {
        float acc = 0.f;
#pragma unroll 16
        for (int k = 0; k < 128; k++) acc += sx[local][k] * sW[k * 32 + j];
        g1[n * 32 + j] = acc * dinv[n];
    }
}

// g2[i][j] = dinv[i] * sum_k h1[i][k]*W2[k][j]   (h1 already relu+bias)
__global__ void gemm2_kernel(const float* __restrict__ h1,
                             const float* __restrict__ dinv,
                             const float* __restrict__ W2,
                             float* __restrict__ g2, int N) {
    __shared__ float sW[32 * 16];
    __shared__ float sin_[16][32];
    for (int i = threadIdx.x; i < 32 * 16; i += BLK) sW[i] = W2[i];
    int node0 = blockIdx.x * 16;
    for (int i = threadIdx.x; i < 16 * 32; i += BLK) {
        int r = i >> 5, c = i & 31;
        int n = node0 + r;
        sin_[r][c] = (n < N) ? h1[n * 32 + c] : 0.f;
    }
    __syncthreads();
    int local = threadIdx.x >> 4;
    int j = threadIdx.x & 15;
    int n = node0 + local;
    if (n < N) {
        float acc = 0.f;
#pragma unroll
        for (int k = 0; k < 32; k++) acc += sin_[local][k] * sW[k * 16 + j];
        g2[n * 16 + j] = acc * dinv[n];
    }
}

// out[i] = h2[i] @ Wout + bout   (h2 already relu'd)
__global__ void final_kernel2(const float* __restrict__ h2,
                              const float* __restrict__ Wout,
                              const float* __restrict__ bout,
                              float* __restrict__ out, int N) {
    int n = blockIdx.x * blockDim.x + threadIdx.x;
    if (n >= N) return;
    float o0 = bout[0], o1 = bout[1], o2 = bout[2];
#pragma unroll
    for (int k = 0; k < 16; k++) {
        float v = h2[n * 16 + k];
        o0 += v * Wout[k * 3 + 0];
        o1 += v * Wout[k * 3 + 1];
        o2 += v * Wout[k * 3 + 2];
    }
    out[n * 3 + 0] = o0;
    out[n * 3 + 1] = o1;
    out[n * 3 + 2] = o2;
}

// ---------------- fallback (exact atomic path) ----------------

__global__ void deg_kernel(const int* __restrict__ dst,
                           const float* __restrict__ w,
                           float* __restrict__ deg, int E) {
    int e = blockIdx.x * blockDim.x + threadIdx.x;
    if (e < E) atomicAdd(&deg[dst[e]], w[e]);
}

__global__ void dinvf_kernel(float* __restrict__ deg, int N) {
    int i = blockIdx.x * blockDim.x + threadIdx.x;
    if (i < N) deg[i] = rsqrtf(deg[i] + 1.0f);
}

template <int F>
__global__ void edge_agg_kernel(const int* __restrict__ src,
                                const int* __restrict__ dst,
                                const float* __restrict__ w,
                                const float* __restrict__ g,
                                float* __restrict__ agg, int E) {
    unsigned idx = blockIdx.x * blockDim.x + threadIdx.x;
    unsigned total = (unsigned)E * F;
    if (idx >= total) return;
    unsigned e = idx / F;
    unsigned f = idx & (F - 1);
    int s = __ldg(&src[e]);
    int d = __ldg(&dst[e]);
    float we = __ldg(&w[e]);
    atomicAdd(&agg[(unsigned)d * F + f], we * g[(unsigned)s * F + f]);
}

__global__ void layer2_kernel(const float* __restrict__ agg1,
                              const float* __restrict__ g1,
                              const float* __restrict__ dinv,
                              const float* __restrict__ b1,
                              const float* __restrict__ W2,
                              float* __restrict__ g2, int N) {
    __shared__ float sW[32 * 16];
    __shared__ float sin_[16][32];
    for (int i = threadIdx.x; i < 32 * 16; i += BLK) sW[i] = W2[i];
    int node0 = blockIdx.x * 16;
    for (int i = threadIdx.x; i < 16 * 32; i += BLK) {
        int r = i >> 5, c = i & 31;
        int n = node0 + r;
        float v = 0.f;
        if (n < N) {
            float di = dinv[n];
            v = fmaxf(di * (agg1[n * 32 + c] + g1[n * 32 + c]) + b1[c], 0.f);
        }
        sin_[r][c] = v;
    }
    __syncthreads();
    int local = threadIdx.x >> 4;
    int j = threadIdx.x & 15;
    int n = node0 + local;
    if (n < N) {
        float acc = 0.f;
#pragma unroll
        for (int k = 0; k < 32; k++) acc += sin_[local][k] * sW[k * 16 + j];
        g2[n * 16 + j] = acc * dinv[n];
    }
}

__global__ void final_kernel(const float* __restrict__ agg2,
                             const float* __restrict__ g2,
                             const float* __restrict__ dinv,
                             const float* __restrict__ b2,
                             const float* __restrict__ Wout,
                             const float* __restrict__ bout,
                             float* __restrict__ out, int N) {
    int n = blockIdx.x * blockDim.x + threadIdx.x;
    if (n >= N) return;
    float di = dinv[n];
    float o0 = bout[0], o1 = bout[1], o2 = bout[2];
#pragma unroll
    for (int k = 0; k < 16; k++) {
        float v = fmaxf(di * (agg2[n * 16 + k] + g2[n * 16 + k]) + b2[k], 0.f);
        o0 += v * Wout[k * 3 + 0];
        o1 += v * Wout[k * 3 + 1];
        o2 += v * Wout[k * 3 + 2];
    }
    out[n * 3 + 0] = o0;
    out[n * 3 + 1] = o1;
    out[n * 3 + 2] = o2;
}

// ---------------------------------------------------------------------------

extern "C" void kernel_launch(void* const* d_in, const int* in_sizes, int n_in,
                              void* d_out, int out_size, void* d_ws, size_t ws_size,
                              hipStream_t stream) {
    const float* x    = (const float*)d_in[0];
    const int* ei     = (const int*)d_in[1];   // [2, E]: row0 = src, row1 = dst
    const float* ew   = (const float*)d_in[2];
    const float* W1   = (const float*)d_in[3];
    const float* b1   = (const float*)d_in[4];
    const float* W2   = (const float*)d_in[5];
    const float* b2   = (const float*)d_in[6];
    const float* Wout = (const float*)d_in[7];
    const float* bout = (const float*)d_in[8];
    float* out = (float*)d_out;

    const int N = in_sizes[0] / 128;
    const int E = in_sizes[2];
    const int* src = ei;
    const int* dst = ei + E;

    const int B = (N + S_NODES - 1) / S_NODES;
    // bucketed workspace (floats): packed 2E | gcnt/gstart/gcur 3*MAXB |
    //                              dinv N | g1 32N | h1 32N | g2 16N | h2 16N
    const size_t need =
        (2 * (size_t)E + 97 * (size_t)N + 3 * MAXB) * sizeof(float);

    if (ws_size >= need && B <= MAXB) {
        float* ws    = (float*)d_ws;
        u64* packed  = (u64*)ws;                     // E u64 (8B aligned)
        int* gcnt    = (int*)(ws + 2 * (size_t)E);   // MAXB
        int* gstart  = gcnt + MAXB;                  // MAXB
        int* gcur    = gstart + MAXB;                // MAXB
        float* dinv  = (float*)(gcur + MAXB);        // N
        float* g1    = dinv + (size_t)N;             // 32N
        float* h1    = g1 + 32 * (size_t)N;          // 32N
        float* g2    = h1 + 32 * (size_t)N;          // 16N
        float* h2    = g2 + 16 * (size_t)N;          // 16N

        // zero only the bucket counters (2 KB)
        hipMemsetAsync(gcnt, 0, MAXB * sizeof(int), stream);

        bucket_count_kernel<<<1024, BLK, 0, stream>>>(dst, gcnt, E);
        bucket_scan_kernel<<<1, BLK, 0, stream>>>(gcnt, gstart, gcur, B);
        partition_kernel<<<(E + CHUNK - 1) / CHUNK, BLK, 0, stream>>>(
            src, dst, ew, gcur, packed, E);
        bucket_deg_kernel<<<B, BLK, 0, stream>>>(packed, gstart, gcnt, dinv, N);

        gemm1_kernel<<<(N + 7) / 8, BLK, 0, stream>>>(x, W1, dinv, g1, N);
        bucket_agg_kernel<32><<<B, BLK, 0, stream>>>(packed, gstart, gcnt, g1,
                                                     dinv, b1, h1, N);
        gemm2_kernel<<<(N + 15) / 16, BLK, 0, stream>>>(h1, dinv, W2, g2, N);
        bucket_agg_kernel<16><<<B, BLK, 0, stream>>>(packed, gstart, gcnt, g2,
                                                     dinv, b2, h2, N);
        final_kernel2<<<(N + BLK - 1) / BLK, BLK, 0, stream>>>(h2, Wout, bout,
                                                               out, N);
    } else {
        // ---------- fallback: proven atomic path ----------
        float* ws   = (float*)d_ws;
        float* deg  = ws;
        float* agg1 = ws + (size_t)N;
        float* agg2 = ws + (size_t)33 * N;
        float* g1   = ws + (size_t)49 * N;
        float* g2   = ws + (size_t)81 * N;

        hipMemsetAsync(ws, 0, (size_t)49 * N * sizeof(float), stream);

        deg_kernel<<<(E + BLK - 1) / BLK, BLK, 0, stream>>>(dst, ew, deg, E);
        dinvf_kernel<<<(N + BLK - 1) / BLK, BLK, 0, stream>>>(deg, N);
        gemm1_kernel<<<(N + 7) / 8, BLK, 0, stream>>>(x, W1, deg, g1, N);
        {
            unsigned total = (unsigned)E * 32u;
            edge_agg_kernel<32><<<(total + BLK - 1) / BLK, BLK, 0, stream>>>(
                src, dst, ew, g1, agg1, E);
        }
        layer2_kernel<<<(N + 15) / 16, BLK, 0, stream>>>(agg1, g1, deg, b1, W2, g2, N);
        {
            unsigned total = (unsigned)E * 16u;
            edge_agg_kernel<16><<<(total + BLK - 1) / BLK, BLK, 0, stream>>>(
                src, dst, ew, g2, agg2, E);
        }
        final_kernel<<<(N + BLK - 1) / BLK, BLK, 0, stream>>>(
            agg2, g2, deg, b2, Wout, bout, out, N);
    }
}

// Round 4
// 413.487 us; speedup vs baseline: 3.1706x; 3.1706x over previous
//
#include <hip/hip_runtime.h>

// ---------------------------------------------------------------------------
// EnterpriseGNN: 3-layer GCN on MI355X.
//   h1 = relu(GCNConv(x, W1, b1));  h2 = relu(GCNConv(h1, W2, b2));
//   out = h2 @ Wout + bout
// GCNConv(x,W,b)[i] = dinv[i] * ( sum_{e:dst=i} w_e * g[src_e] + g[i] ) + b
//   where g = dinv .* (x@W),  dinv = rsqrt(deg+1), deg = sum_{e:dst=i} w_e.
//
// R4: two-level CSR build + R2's high-parallelism gather.
//  - R3 lesson: 391-block bucket aggregation = 13% occupancy = latency death.
//    Aggregation MUST be the N/8-block gather (R2, ~120us).
//  - R2 lesson: node-granular scattered fabric ops cost ~130us/class
//    (hist 140, scatter 260). Build CSR hierarchically instead:
//      bucket_count (LDS hist) -> partition into 256-node regions
//      (coalesced runs) -> per-bucket LDS counting-sort (scattered writes
//      confined to L2-resident 64KB windows) -> exact CSR + dinv for free.
//  - packed (dead after sort) is reused for g1/g2 to keep ws <= ~72MB.
// ---------------------------------------------------------------------------

#define BLK 256
#define S_NODES 256        // nodes per bucket
#define MAXB 512           // max buckets -> supports N <= 131072
#define CHUNK 8192         // edges per partition block

typedef unsigned long long u64;
typedef unsigned int u32;

// ---------------- build kernels ----------------

// per-bucket edge counts (LDS histogram, tiny global flush)
__global__ void bucket_count_kernel(const int* __restrict__ dst,
                                    int* __restrict__ gcnt, int E) {
    __shared__ int h[MAXB];
    for (int i = threadIdx.x; i < MAXB; i += BLK) h[i] = 0;
    __syncthreads();
    int stride = gridDim.x * blockDim.x;
    for (int e = blockIdx.x * blockDim.x + threadIdx.x; e < E; e += stride)
        atomicAdd(&h[dst[e] >> 8], 1);
    __syncthreads();
    for (int i = threadIdx.x; i < MAXB; i += BLK)
        if (h[i]) atomicAdd(&gcnt[i], h[i]);
}

// single block: exclusive scan of gcnt[B] -> gstart, gcur
__global__ void bucket_scan_kernel(const int* __restrict__ gcnt,
                                   int* __restrict__ gstart,
                                   int* __restrict__ gcur, int B) {
    __shared__ int s[MAXB];
    for (int i = threadIdx.x; i < B; i += BLK) s[i] = gcnt[i];
    __syncthreads();
    if (threadIdx.x == 0) {
        int run = 0;
        for (int i = 0; i < B; i++) { int v = s[i]; s[i] = run; run += v; }
    }
    __syncthreads();
    for (int i = threadIdx.x; i < B; i += BLK) { gstart[i] = s[i]; gcur[i] = s[i]; }
}

// partition edges into bucket regions; within-bucket order arbitrary.
// record: [w:32][dst_local:8][src:24]
__global__ void partition_kernel(const int* __restrict__ src,
                                 const int* __restrict__ dst,
                                 const float* __restrict__ w,
                                 int* __restrict__ gcur,
                                 u64* __restrict__ packed, int E) {
    __shared__ int lcnt[MAXB];
    __shared__ int lbase[MAXB];
    int e0 = blockIdx.x * CHUNK;
    int e1 = min(e0 + CHUNK, E);
    for (int i = threadIdx.x; i < MAXB; i += BLK) lcnt[i] = 0;
    __syncthreads();
    for (int e = e0 + threadIdx.x; e < e1; e += BLK)
        atomicAdd(&lcnt[dst[e] >> 8], 1);
    __syncthreads();
    // reserve contiguous global run per bucket for this block
    for (int b = threadIdx.x; b < MAXB; b += BLK) {
        int c = lcnt[b];
        lbase[b] = c ? atomicAdd(&gcur[b], c) : 0;
    }
    __syncthreads();
    for (int i = threadIdx.x; i < MAXB; i += BLK) lcnt[i] = 0;  // reuse as cursor
    __syncthreads();
    for (int e = e0 + threadIdx.x; e < e1; e += BLK) {
        int d = dst[e];
        int b = d >> 8;
        int pos = lbase[b] + atomicAdd(&lcnt[b], 1);
        u64 rec = ((u64)__float_as_uint(w[e]) << 32) |
                  ((u64)(u32)(d & 255) << 24) | (u32)src[e];
        packed[pos] = rec;
    }
}

// per-bucket LDS counting-sort: bucket region (L2-resident ~64KB) -> exact
// per-node CSR order in packed2; emits rowstart/rowend/dinv.
__global__ void bucket_sort_kernel(const u64* __restrict__ packed,
                                   const int* __restrict__ gstart,
                                   const int* __restrict__ gcnt,
                                   u64* __restrict__ packed2,
                                   int* __restrict__ rowA,
                                   int* __restrict__ rowB,
                                   float* __restrict__ dinv, int N) {
    __shared__ int cnt[S_NODES];
    __shared__ int scan[S_NODES];
    __shared__ int cur[S_NODES];
    __shared__ float sacc[S_NODES];
    int b = blockIdx.x;
    int n0 = b << 8;
    int s = gstart[b];
    int e = s + gcnt[b];
    int t = threadIdx.x;
    cnt[t] = 0;
    sacc[t] = 0.f;
    __syncthreads();
    // pass A: count per-node + weight sums
    for (int i = s + t; i < e; i += BLK) {
        u64 rec = packed[i];
        int ln = (int)((rec >> 24) & 255);
        atomicAdd(&cnt[ln], 1);
        atomicAdd(&sacc[ln], __uint_as_float((u32)(rec >> 32)));
    }
    __syncthreads();
    // exclusive scan over 256 counters (Hillis-Steele inclusive, then shift)
    int v = cnt[t];
    scan[t] = v;
    __syncthreads();
    for (int d = 1; d < S_NODES; d <<= 1) {
        int xv = (t >= d) ? scan[t - d] : 0;
        __syncthreads();
        scan[t] += xv;
        __syncthreads();
    }
    int excl = scan[t] - v;
    int n = n0 + t;
    if (n < N) {
        rowA[n] = s + excl;
        rowB[n] = s + excl + v;
        dinv[n] = rsqrtf(sacc[t] + 1.0f);
    }
    cur[t] = s + excl;
    __syncthreads();
    // pass B: place records (writes land inside this bucket's 64KB window)
    for (int i = s + t; i < e; i += BLK) {
        u64 rec = packed[i];
        int ln = (int)((rec >> 24) & 255);
        int pos = atomicAdd(&cur[ln], 1);
        packed2[pos] = rec;
    }
}

// per-node gather aggregation + fused GCN epilogue (R2 engine):
//   h[n][f] = relu( dinv[n] * (sum_e w_e * g[src_e][f] + g[n][f]) + bias[f] )
template <int F>
__global__ void gather_kernel(const u64* __restrict__ packed,
                              const int* __restrict__ A,
                              const int* __restrict__ Bend,
                              const float* __restrict__ g,
                              const float* __restrict__ dinv,
                              const float* __restrict__ bias,
                              float* __restrict__ h, int N) {
    const int NPB = BLK / F;
    int f = threadIdx.x & (F - 1);
    int local = threadIdx.x / F;
    int n = blockIdx.x * NPB + local;
    if (n >= N) return;
    int s = A[n], e = Bend[n];
    float acc = g[(size_t)n * F + f];  // self loop, weight 1
    int i = s;
    for (; i + 4 <= e; i += 4) {       // 4-deep MLP on the L2/L3 gathers
        u64 p0 = packed[i], p1 = packed[i + 1];
        u64 p2 = packed[i + 2], p3 = packed[i + 3];
        float ga = g[(size_t)(u32)(p0 & 0xFFFFFF) * F + f];
        float gb = g[(size_t)(u32)(p1 & 0xFFFFFF) * F + f];
        float gc = g[(size_t)(u32)(p2 & 0xFFFFFF) * F + f];
        float gd = g[(size_t)(u32)(p3 & 0xFFFFFF) * F + f];
        acc += __uint_as_float((u32)(p0 >> 32)) * ga;
        acc += __uint_as_float((u32)(p1 >> 32)) * gb;
        acc += __uint_as_float((u32)(p2 >> 32)) * gc;
        acc += __uint_as_float((u32)(p3 >> 32)) * gd;
    }
    for (; i < e; ++i) {
        u64 p = packed[i];
        acc += __uint_as_float((u32)(p >> 32)) * g[(size_t)(u32)(p & 0xFFFFFF) * F + f];
    }
    h[(size_t)n * F + f] = fmaxf(dinv[n] * acc + bias[f], 0.f);
}

// g1[i][j] = dinv[i] * sum_k x[i][k] * W1[k][j]   (128 -> 32)
__global__ void gemm1_kernel(const float* __restrict__ x,
                             const float* __restrict__ W1,
                             const float* __restrict__ dinv,
                             float* __restrict__ g1, int N) {
    __shared__ float sW[128 * 32];   // 16 KB
    __shared__ float sx[8][128];     // 4 KB
    const float4* W4 = (const float4*)W1;
    float4* sW4 = (float4*)sW;
    for (int i = threadIdx.x; i < 1024; i += BLK) sW4[i] = W4[i];
    int node0 = blockIdx.x * 8;
    {
        int r = threadIdx.x >> 5, c4 = threadIdx.x & 31;  // 8 rows x 32 float4
        int n = node0 + r;
        float4 v = make_float4(0.f, 0.f, 0.f, 0.f);
        if (n < N) v = *(const float4*)&x[(size_t)n * 128 + c4 * 4];
        *(float4*)&sx[r][c4 * 4] = v;
    }
    __syncthreads();
    int local = threadIdx.x >> 5;     // node within block (0..7)
    int j = threadIdx.x & 31;         // output feature
    int n = node0 + local;
    if (n < N) {
        float acc = 0.f;
#pragma unroll 16
        for (int k = 0; k < 128; k++) acc += sx[local][k] * sW[k * 32 + j];
        g1[n * 32 + j] = acc * dinv[n];
    }
}

// g2[i][j] = dinv[i] * sum_k h1[i][k]*W2[k][j]   (h1 already relu+bias)
__global__ void gemm2_kernel(const float* __restrict__ h1,
                             const float* __restrict__ dinv,
                             const float* __restrict__ W2,
                             float* __restrict__ g2, int N) {
    __shared__ float sW[32 * 16];
    __shared__ float sin_[16][32];
    for (int i = threadIdx.x; i < 32 * 16; i += BLK) sW[i] = W2[i];
    int node0 = blockIdx.x * 16;
    for (int i = threadIdx.x; i < 16 * 32; i += BLK) {
        int r = i >> 5, c = i & 31;
        int n = node0 + r;
        sin_[r][c] = (n < N) ? h1[n * 32 + c] : 0.f;
    }
    __syncthreads();
    int local = threadIdx.x >> 4;
    int j = threadIdx.x & 15;
    int n = node0 + local;
    if (n < N) {
        float acc = 0.f;
#pragma unroll
        for (int k = 0; k < 32; k++) acc += sin_[local][k] * sW[k * 16 + j];
        g2[n * 16 + j] = acc * dinv[n];
    }
}

// out[i] = h2[i] @ Wout + bout   (h2 already relu'd)
__global__ void final_kernel2(const float* __restrict__ h2,
                              const float* __restrict__ Wout,
                              const float* __restrict__ bout,
                              float* __restrict__ out, int N) {
    int n = blockIdx.x * blockDim.x + threadIdx.x;
    if (n >= N) return;
    float o0 = bout[0], o1 = bout[1], o2 = bout[2];
#pragma unroll
    for (int k = 0; k < 16; k++) {
        float v = h2[n * 16 + k];
        o0 += v * Wout[k * 3 + 0];
        o1 += v * Wout[k * 3 + 1];
        o2 += v * Wout[k * 3 + 2];
    }
    out[n * 3 + 0] = o0;
    out[n * 3 + 1] = o1;
    out[n * 3 + 2] = o2;
}

// ---------------- fallback (exact atomic path) ----------------

__global__ void deg_kernel(const int* __restrict__ dst,
                           const float* __restrict__ w,
                           float* __restrict__ deg, int E) {
    int e = blockIdx.x * blockDim.x + threadIdx.x;
    if (e < E) atomicAdd(&deg[dst[e]], w[e]);
}

__global__ void dinvf_kernel(float* __restrict__ deg, int N) {
    int i = blockIdx.x * blockDim.x + threadIdx.x;
    if (i < N) deg[i] = rsqrtf(deg[i] + 1.0f);
}

template <int F>
__global__ void edge_agg_kernel(const int* __restrict__ src,
                                const int* __restrict__ dst,
                                const float* __restrict__ w,
                                const float* __restrict__ g,
                                float* __restrict__ agg, int E) {
    unsigned idx = blockIdx.x * blockDim.x + threadIdx.x;
    unsigned total = (unsigned)E * F;
    if (idx >= total) return;
    unsigned e = idx / F;
    unsigned f = idx & (F - 1);
    int s = __ldg(&src[e]);
    int d = __ldg(&dst[e]);
    float we = __ldg(&w[e]);
    atomicAdd(&agg[(unsigned)d * F + f], we * g[(unsigned)s * F + f]);
}

__global__ void layer2_kernel(const float* __restrict__ agg1,
                              const float* __restrict__ g1,
                              const float* __restrict__ dinv,
                              const float* __restrict__ b1,
                              const float* __restrict__ W2,
                              float* __restrict__ g2, int N) {
    __shared__ float sW[32 * 16];
    __shared__ float sin_[16][32];
    for (int i = threadIdx.x; i < 32 * 16; i += BLK) sW[i] = W2[i];
    int node0 = blockIdx.x * 16;
    for (int i = threadIdx.x; i < 16 * 32; i += BLK) {
        int r = i >> 5, c = i & 31;
        int n = node0 + r;
        float v = 0.f;
        if (n < N) {
            float di = dinv[n];
            v = fmaxf(di * (agg1[n * 32 + c] + g1[n * 32 + c]) + b1[c], 0.f);
        }
        sin_[r][c] = v;
    }
    __syncthreads();
    int local = threadIdx.x >> 4;
    int j = threadIdx.x & 15;
    int n = node0 + local;
    if (n < N) {
        float acc = 0.f;
#pragma unroll
        for (int k = 0; k < 32; k++) acc += sin_[local][k] * sW[k * 16 + j];
        g2[n * 16 + j] = acc * dinv[n];
    }
}

__global__ void final_kernel(const float* __restrict__ agg2,
                             const float* __restrict__ g2,
                             const float* __restrict__ dinv,
                             const float* __restrict__ b2,
                             const float* __restrict__ Wout,
                             const float* __restrict__ bout,
                             float* __restrict__ out, int N) {
    int n = blockIdx.x * blockDim.x + threadIdx.x;
    if (n >= N) return;
    float di = dinv[n];
    float o0 = bout[0], o1 = bout[1], o2 = bout[2];
#pragma unroll
    for (int k = 0; k < 16; k++) {
        float v = fmaxf(di * (agg2[n * 16 + k] + g2[n * 16 + k]) + b2[k], 0.f);
        o0 += v * Wout[k * 3 + 0];
        o1 += v * Wout[k * 3 + 1];
        o2 += v * Wout[k * 3 + 2];
    }
    out[n * 3 + 0] = o0;
    out[n * 3 + 1] = o1;
    out[n * 3 + 2] = o2;
}

// ---------------------------------------------------------------------------

extern "C" void kernel_launch(void* const* d_in, const int* in_sizes, int n_in,
                              void* d_out, int out_size, void* d_ws, size_t ws_size,
                              hipStream_t stream) {
    const float* x    = (const float*)d_in[0];
    const int* ei     = (const int*)d_in[1];   // [2, E]: row0 = src, row1 = dst
    const float* ew   = (const float*)d_in[2];
    const float* W1   = (const float*)d_in[3];
    const float* b1   = (const float*)d_in[4];
    const float* W2   = (const float*)d_in[5];
    const float* b2   = (const float*)d_in[6];
    const float* Wout = (const float*)d_in[7];
    const float* bout = (const float*)d_in[8];
    float* out = (float*)d_out;

    const int N = in_sizes[0] / 128;
    const int E = in_sizes[2];
    const int* src = ei;
    const int* dst = ei + E;

    const int B = (N + S_NODES - 1) / S_NODES;
    // workspace (floats):
    //   regionA 2E  : packed during build; g1 (32N) + g2 (16N) after sort
    //   packed2 2E  : sorted records (live through gather<16>)
    //   rowA N | rowB N | dinv N | h1 32N | h2 16N | gcnt/gstart/gcur 3*MAXB
    const size_t need =
        (4 * (size_t)E + 51 * (size_t)N + 3 * MAXB) * sizeof(float);
    const bool reuse_ok = (2 * (size_t)E >= 48 * (size_t)N);

    if (ws_size >= need && B <= MAXB && reuse_ok) {
        float* ws     = (float*)d_ws;
        u64* packed   = (u64*)ws;                      // 2E floats (regionA)
        float* g1     = ws;                            // 32N (after sort)
        float* g2     = ws + 32 * (size_t)N;           // 16N (after sort)
        u64* packed2  = (u64*)(ws + 2 * (size_t)E);    // 2E floats
        int* rowA     = (int*)(ws + 4 * (size_t)E);    // N
        int* rowB     = rowA + N;                      // N
        float* dinv   = (float*)(rowB + N);            // N
        float* h1     = dinv + (size_t)N;              // 32N
        float* h2     = h1 + 32 * (size_t)N;           // 16N
        int* gcnt     = (int*)(h2 + 16 * (size_t)N);   // MAXB
        int* gstart   = gcnt + MAXB;                   // MAXB
        int* gcur     = gstart + MAXB;                 // MAXB

        // zero only the bucket counters (2 KB)
        hipMemsetAsync(gcnt, 0, MAXB * sizeof(int), stream);

        bucket_count_kernel<<<1024, BLK, 0, stream>>>(dst, gcnt, E);
        bucket_scan_kernel<<<1, BLK, 0, stream>>>(gcnt, gstart, gcur, B);
        partition_kernel<<<(E + CHUNK - 1) / CHUNK, BLK, 0, stream>>>(
            src, dst, ew, gcur, packed, E);
        bucket_sort_kernel<<<B, BLK, 0, stream>>>(packed, gstart, gcnt,
                                                  packed2, rowA, rowB, dinv, N);
        // packed (regionA) dead from here; g1/g2 overlay it.

        gemm1_kernel<<<(N + 7) / 8, BLK, 0, stream>>>(x, W1, dinv, g1, N);
        gather_kernel<32><<<(N + 7) / 8, BLK, 0, stream>>>(packed2, rowA, rowB,
                                                           g1, dinv, b1, h1, N);
        gemm2_kernel<<<(N + 15) / 16, BLK, 0, stream>>>(h1, dinv, W2, g2, N);
        gather_kernel<16><<<(N + 15) / 16, BLK, 0, stream>>>(packed2, rowA, rowB,
                                                             g2, dinv, b2, h2, N);
        final_kernel2<<<(N + BLK - 1) / BLK, BLK, 0, stream>>>(h2, Wout, bout,
                                                               out, N);
    } else {
        // ---------- fallback: proven atomic path ----------
        float* ws   = (float*)d_ws;
        float* deg  = ws;
        float* agg1 = ws + (size_t)N;
        float* agg2 = ws + (size_t)33 * N;
        float* g1   = ws + (size_t)49 * N;
        float* g2   = ws + (size_t)81 * N;

        hipMemsetAsync(ws, 0, (size_t)49 * N * sizeof(float), stream);

        deg_kernel<<<(E + BLK - 1) / BLK, BLK, 0, stream>>>(dst, ew, deg, E);
        dinvf_kernel<<<(N + BLK - 1) / BLK, BLK, 0, stream>>>(deg, N);
        gemm1_kernel<<<(N + 7) / 8, BLK, 0, stream>>>(x, W1, deg, g1, N);
        {
            unsigned total = (unsigned)E * 32u;
            edge_agg_kernel<32><<<(total + BLK - 1) / BLK, BLK, 0, stream>>>(
                src, dst, ew, g1, agg1, E);
        }
        layer2_kernel<<<(N + 15) / 16, BLK, 0, stream>>>(agg1, g1, deg, b1, W2, g2, N);
        {
            unsigned total = (unsigned)E * 16u;
            edge_agg_kernel<16><<<(total + BLK - 1) / BLK, BLK, 0, stream>>>(
                src, dst, ew, g2, agg2, E);
        }
        final_kernel<<<(N + BLK - 1) / BLK, BLK, 0, stream>>>(
            agg2, g2, deg, b2, Wout, bout, out, N);
    }
}

// Round 6
// 398.551 us; speedup vs baseline: 3.2894x; 1.0375x over previous
//
#include <hip/hip_runtime.h>

// ---------------------------------------------------------------------------
// EnterpriseGNN: 3-layer GCN on MI355X.
//   h1 = relu(GCNConv(x, W1, b1));  h2 = relu(GCNConv(h1, W2, b2));
//   out = h2 @ Wout + bout
// GCNConv(x,W,b)[i] = dinv[i] * ( sum_{e:dst=i} w_e * g[src_e] + g[i] ) + b
//   where g = dinv .* (x@W),  dinv = rsqrt(deg+1), deg = sum_{e:dst=i} w_e.
//
// R4: two-level CSR build (bucket partition -> per-bucket LDS counting sort)
//     + R2's high-parallelism per-node gather. 413us.
// R5: partition & sort were 391-block launches at 13.8% occupancy
//     (latency-bound). Widen both to 1024-thread blocks (16 waves): 391x16
//     waves = 76% device occupancy with IDENTICAL memory access pattern
//     (same run lengths, same LDS counting-sort footprint).
// R6: resubmission of R5 — the R5 bench died to a container/broker failure
//     (no compile/correctness/timeout signal); code re-audited for
//     hang/crash vectors (uniform syncs, bounded writes, launch limits) and
//     resubmitted unchanged to get the A/B measurement.
// ---------------------------------------------------------------------------

#define BLK 256
#define BLKW 1024          // wide blocks for the 391-block build kernels
#define S_NODES 256        // nodes per bucket
#define MAXB 512           // max buckets -> supports N <= 131072
#define CHUNK 8192         // edges per partition block

typedef unsigned long long u64;
typedef unsigned int u32;

// ---------------- build kernels ----------------

// per-bucket edge counts (LDS histogram, tiny global flush)
__global__ void bucket_count_kernel(const int* __restrict__ dst,
                                    int* __restrict__ gcnt, int E) {
    __shared__ int h[MAXB];
    for (int i = threadIdx.x; i < MAXB; i += BLK) h[i] = 0;
    __syncthreads();
    int stride = gridDim.x * blockDim.x;
    for (int e = blockIdx.x * blockDim.x + threadIdx.x; e < E; e += stride)
        atomicAdd(&h[dst[e] >> 8], 1);
    __syncthreads();
    for (int i = threadIdx.x; i < MAXB; i += BLK)
        if (h[i]) atomicAdd(&gcnt[i], h[i]);
}

// single block: exclusive scan of gcnt[B] -> gstart, gcur
__global__ void bucket_scan_kernel(const int* __restrict__ gcnt,
                                   int* __restrict__ gstart,
                                   int* __restrict__ gcur, int B) {
    __shared__ int s[MAXB];
    for (int i = threadIdx.x; i < B; i += BLK) s[i] = gcnt[i];
    __syncthreads();
    if (threadIdx.x == 0) {
        int run = 0;
        for (int i = 0; i < B; i++) { int v = s[i]; s[i] = run; run += v; }
    }
    __syncthreads();
    for (int i = threadIdx.x; i < B; i += BLK) { gstart[i] = s[i]; gcur[i] = s[i]; }
}

// partition edges into bucket regions; within-bucket order arbitrary.
// record: [w:32][dst_local:8][src:24]
__global__ __launch_bounds__(BLKW)
void partition_kernel(const int* __restrict__ src,
                      const int* __restrict__ dst,
                      const float* __restrict__ w,
                      int* __restrict__ gcur,
                      u64* __restrict__ packed, int E) {
    __shared__ int lcnt[MAXB];
    __shared__ int lbase[MAXB];
    int e0 = blockIdx.x * CHUNK;
    int e1 = min(e0 + CHUNK, E);
    for (int i = threadIdx.x; i < MAXB; i += BLKW) lcnt[i] = 0;
    __syncthreads();
    for (int e = e0 + threadIdx.x; e < e1; e += BLKW)
        atomicAdd(&lcnt[dst[e] >> 8], 1);
    __syncthreads();
    // reserve contiguous global run per bucket for this block
    for (int b = threadIdx.x; b < MAXB; b += BLKW) {
        int c = lcnt[b];
        lbase[b] = c ? atomicAdd(&gcur[b], c) : 0;
    }
    __syncthreads();
    for (int i = threadIdx.x; i < MAXB; i += BLKW) lcnt[i] = 0;  // reuse as cursor
    __syncthreads();
    for (int e = e0 + threadIdx.x; e < e1; e += BLKW) {
        int d = dst[e];
        int b = d >> 8;
        int pos = lbase[b] + atomicAdd(&lcnt[b], 1);
        u64 rec = ((u64)__float_as_uint(w[e]) << 32) |
                  ((u64)(u32)(d & 255) << 24) | (u32)src[e];
        packed[pos] = rec;
    }
}

// per-bucket LDS counting-sort: bucket region (L2-resident ~64KB) -> exact
// per-node CSR order in packed2; emits rowstart/rowend/dinv.
__global__ __launch_bounds__(BLKW)
void bucket_sort_kernel(const u64* __restrict__ packed,
                        const int* __restrict__ gstart,
                        const int* __restrict__ gcnt,
                        u64* __restrict__ packed2,
                        int* __restrict__ rowA,
                        int* __restrict__ rowB,
                        float* __restrict__ dinv, int N) {
    __shared__ int cnt[S_NODES];
    __shared__ int scan[S_NODES];
    __shared__ int cur[S_NODES];
    __shared__ float sacc[S_NODES];
    int b = blockIdx.x;
    int n0 = b << 8;
    int s = gstart[b];
    int e = s + gcnt[b];
    int t = threadIdx.x;
    if (t < S_NODES) { cnt[t] = 0; sacc[t] = 0.f; }
    __syncthreads();
    // pass A: count per-node + weight sums
    for (int i = s + t; i < e; i += BLKW) {
        u64 rec = packed[i];
        int ln = (int)((rec >> 24) & 255);
        atomicAdd(&cnt[ln], 1);
        atomicAdd(&sacc[ln], __uint_as_float((u32)(rec >> 32)));
    }
    __syncthreads();
    // exclusive scan over 256 counters (guarded Hillis-Steele; uniform syncs)
    int v = 0;
    if (t < S_NODES) { v = cnt[t]; scan[t] = v; }
    __syncthreads();
    for (int d = 1; d < S_NODES; d <<= 1) {
        int xv = 0;
        if (t >= d && t < S_NODES) xv = scan[t - d];
        __syncthreads();
        if (t < S_NODES) scan[t] += xv;
        __syncthreads();
    }
    if (t < S_NODES) {
        int excl = scan[t] - v;
        int n = n0 + t;
        if (n < N) {
            rowA[n] = s + excl;
            rowB[n] = s + excl + v;
            dinv[n] = rsqrtf(sacc[t] + 1.0f);
        }
        cur[t] = s + excl;
    }
    __syncthreads();
    // pass B: place records (writes land inside this bucket's 64KB window)
    for (int i = s + t; i < e; i += BLKW) {
        u64 rec = packed[i];
        int ln = (int)((rec >> 24) & 255);
        int pos = atomicAdd(&cur[ln], 1);
        packed2[pos] = rec;
    }
}

// per-node gather aggregation + fused GCN epilogue (R2 engine):
//   h[n][f] = relu( dinv[n] * (sum_e w_e * g[src_e][f] + g[n][f]) + bias[f] )
template <int F>
__global__ void gather_kernel(const u64* __restrict__ packed,
                              const int* __restrict__ A,
                              const int* __restrict__ Bend,
                              const float* __restrict__ g,
                              const float* __restrict__ dinv,
                              const float* __restrict__ bias,
                              float* __restrict__ h, int N) {
    const int NPB = BLK / F;
    int f = threadIdx.x & (F - 1);
    int local = threadIdx.x / F;
    int n = blockIdx.x * NPB + local;
    if (n >= N) return;
    int s = A[n], e = Bend[n];
    float acc = g[(size_t)n * F + f];  // self loop, weight 1
    int i = s;
    for (; i + 4 <= e; i += 4) {       // 4-deep MLP on the L2/L3 gathers
        u64 p0 = packed[i], p1 = packed[i + 1];
        u64 p2 = packed[i + 2], p3 = packed[i + 3];
        float ga = g[(size_t)(u32)(p0 & 0xFFFFFF) * F + f];
        float gb = g[(size_t)(u32)(p1 & 0xFFFFFF) * F + f];
        float gc = g[(size_t)(u32)(p2 & 0xFFFFFF) * F + f];
        float gd = g[(size_t)(u32)(p3 & 0xFFFFFF) * F + f];
        acc += __uint_as_float((u32)(p0 >> 32)) * ga;
        acc += __uint_as_float((u32)(p1 >> 32)) * gb;
        acc += __uint_as_float((u32)(p2 >> 32)) * gc;
        acc += __uint_as_float((u32)(p3 >> 32)) * gd;
    }
    for (; i < e; ++i) {
        u64 p = packed[i];
        acc += __uint_as_float((u32)(p >> 32)) * g[(size_t)(u32)(p & 0xFFFFFF) * F + f];
    }
    h[(size_t)n * F + f] = fmaxf(dinv[n] * acc + bias[f], 0.f);
}

// g1[i][j] = dinv[i] * sum_k x[i][k] * W1[k][j]   (128 -> 32)
__global__ void gemm1_kernel(const float* __restrict__ x,
                             const float* __restrict__ W1,
                             const float* __restrict__ dinv,
                             float* __restrict__ g1, int N) {
    __shared__ float sW[128 * 32];   // 16 KB
    __shared__ float sx[8][128];     // 4 KB
    const float4* W4 = (const float4*)W1;
    float4* sW4 = (float4*)sW;
    for (int i = threadIdx.x; i < 1024; i += BLK) sW4[i] = W4[i];
    int node0 = blockIdx.x * 8;
    {
        int r = threadIdx.x >> 5, c4 = threadIdx.x & 31;  // 8 rows x 32 float4
        int n = node0 + r;
        float4 v = make_float4(0.f, 0.f, 0.f, 0.f);
        if (n < N) v = *(const float4*)&x[(size_t)n * 128 + c4 * 4];
        *(float4*)&sx[r][c4 * 4] = v;
    }
    __syncthreads();
    int local = threadIdx.x >> 5;     // node within block (0..7)
    int j = threadIdx.x & 31;         // output feature
    int n = node0 + local;
    if (n < N) {
        float acc = 0.f;
#pragma unroll 16
        for (int k = 0; k < 128; k++) acc += sx[local][k] * sW[k * 32 + j];
        g1[n * 32 + j] = acc * dinv[n];
    }
}

// g2[i][j] = dinv[i] * sum_k h1[i][k]*W2[k][j]   (h1 already relu+bias)
__global__ void gemm2_kernel(const float* __restrict__ h1,
                             const float* __restrict__ dinv,
                             const float* __restrict__ W2,
                             float* __restrict__ g2, int N) {
    __shared__ float sW[32 * 16];
    __shared__ float sin_[16][32];
    for (int i = threadIdx.x; i < 32 * 16; i += BLK) sW[i] = W2[i];
    int node0 = blockIdx.x * 16;
    for (int i = threadIdx.x; i < 16 * 32; i += BLK) {
        int r = i >> 5, c = i & 31;
        int n = node0 + r;
        sin_[r][c] = (n < N) ? h1[n * 32 + c] : 0.f;
    }
    __syncthreads();
    int local = threadIdx.x >> 4;
    int j = threadIdx.x & 15;
    int n = node0 + local;
    if (n < N) {
        float acc = 0.f;
#pragma unroll
        for (int k = 0; k < 32; k++) acc += sin_[local][k] * sW[k * 16 + j];
        g2[n * 16 + j] = acc * dinv[n];
    }
}

// out[i] = h2[i] @ Wout + bout   (h2 already relu'd)
__global__ void final_kernel2(const float* __restrict__ h2,
                              const float* __restrict__ Wout,
                              const float* __restrict__ bout,
                              float* __restrict__ out, int N) {
    int n = blockIdx.x * blockDim.x + threadIdx.x;
    if (n >= N) return;
    float o0 = bout[0], o1 = bout[1], o2 = bout[2];
#pragma unroll
    for (int k = 0; k < 16; k++) {
        float v = h2[n * 16 + k];
        o0 += v * Wout[k * 3 + 0];
        o1 += v * Wout[k * 3 + 1];
        o2 += v * Wout[k * 3 + 2];
    }
    out[n * 3 + 0] = o0;
    out[n * 3 + 1] = o1;
    out[n * 3 + 2] = o2;
}

// ---------------- fallback (exact atomic path) ----------------

__global__ void deg_kernel(const int* __restrict__ dst,
                           const float* __restrict__ w,
                           float* __restrict__ deg, int E) {
    int e = blockIdx.x * blockDim.x + threadIdx.x;
    if (e < E) atomicAdd(&deg[dst[e]], w[e]);
}

__global__ void dinvf_kernel(float* __restrict__ deg, int N) {
    int i = blockIdx.x * blockDim.x + threadIdx.x;
    if (i < N) deg[i] = rsqrtf(deg[i] + 1.0f);
}

template <int F>
__global__ void edge_agg_kernel(const int* __restrict__ src,
                                const int* __restrict__ dst,
                                const float* __restrict__ w,
                                const float* __restrict__ g,
                                float* __restrict__ agg, int E) {
    unsigned idx = blockIdx.x * blockDim.x + threadIdx.x;
    unsigned total = (unsigned)E * F;
    if (idx >= total) return;
    unsigned e = idx / F;
    unsigned f = idx & (F - 1);
    int s = __ldg(&src[e]);
    int d = __ldg(&dst[e]);
    float we = __ldg(&w[e]);
    atomicAdd(&agg[(unsigned)d * F + f], we * g[(unsigned)s * F + f]);
}

__global__ void layer2_kernel(const float* __restrict__ agg1,
                              const float* __restrict__ g1,
                              const float* __restrict__ dinv,
                              const float* __restrict__ b1,
                              const float* __restrict__ W2,
                              float* __restrict__ g2, int N) {
    __shared__ float sW[32 * 16];
    __shared__ float sin_[16][32];
    for (int i = threadIdx.x; i < 32 * 16; i += BLK) sW[i] = W2[i];
    int node0 = blockIdx.x * 16;
    for (int i = threadIdx.x; i < 16 * 32; i += BLK) {
        int r = i >> 5, c = i & 31;
        int n = node0 + r;
        float v = 0.f;
        if (n < N) {
            float di = dinv[n];
            v = fmaxf(di * (agg1[n * 32 + c] + g1[n * 32 + c]) + b1[c], 0.f);
        }
        sin_[r][c] = v;
    }
    __syncthreads();
    int local = threadIdx.x >> 4;
    int j = threadIdx.x & 15;
    int n = node0 + local;
    if (n < N) {
        float acc = 0.f;
#pragma unroll
        for (int k = 0; k < 32; k++) acc += sin_[local][k] * sW[k * 16 + j];
        g2[n * 16 + j] = acc * dinv[n];
    }
}

__global__ void final_kernel(const float* __restrict__ agg2,
                             const float* __restrict__ g2,
                             const float* __restrict__ dinv,
                             const float* __restrict__ b2,
                             const float* __restrict__ Wout,
                             const float* __restrict__ bout,
                             float* __restrict__ out, int N) {
    int n = blockIdx.x * blockDim.x + threadIdx.x;
    if (n >= N) return;
    float di = dinv[n];
    float o0 = bout[0], o1 = bout[1], o2 = bout[2];
#pragma unroll
    for (int k = 0; k < 16; k++) {
        float v = fmaxf(di * (agg2[n * 16 + k] + g2[n * 16 + k]) + b2[k], 0.f);
        o0 += v * Wout[k * 3 + 0];
        o1 += v * Wout[k * 3 + 1];
        o2 += v * Wout[k * 3 + 2];
    }
    out[n * 3 + 0] = o0;
    out[n * 3 + 1] = o1;
    out[n * 3 + 2] = o2;
}

// ---------------------------------------------------------------------------

extern "C" void kernel_launch(void* const* d_in, const int* in_sizes, int n_in,
                              void* d_out, int out_size, void* d_ws, size_t ws_size,
                              hipStream_t stream) {
    const float* x    = (const float*)d_in[0];
    const int* ei     = (const int*)d_in[1];   // [2, E]: row0 = src, row1 = dst
    const float* ew   = (const float*)d_in[2];
    const float* W1   = (const float*)d_in[3];
    const float* b1   = (const float*)d_in[4];
    const float* W2   = (const float*)d_in[5];
    const float* b2   = (const float*)d_in[6];
    const float* Wout = (const float*)d_in[7];
    const float* bout = (const float*)d_in[8];
    float* out = (float*)d_out;

    const int N = in_sizes[0] / 128;
    const int E = in_sizes[2];
    const int* src = ei;
    const int* dst = ei + E;

    const int B = (N + S_NODES - 1) / S_NODES;
    // workspace (floats):
    //   regionA 2E  : packed during build; g1 (32N) + g2 (16N) after sort
    //   packed2 2E  : sorted records (live through gather<16>)
    //   rowA N | rowB N | dinv N | h1 32N | h2 16N | gcnt/gstart/gcur 3*MAXB
    const size_t need =
        (4 * (size_t)E + 51 * (size_t)N + 3 * MAXB) * sizeof(float);
    const bool reuse_ok = (2 * (size_t)E >= 48 * (size_t)N);

    if (ws_size >= need && B <= MAXB && reuse_ok) {
        float* ws     = (float*)d_ws;
        u64* packed   = (u64*)ws;                      // 2E floats (regionA)
        float* g1     = ws;                            // 32N (after sort)
        float* g2     = ws + 32 * (size_t)N;           // 16N (after sort)
        u64* packed2  = (u64*)(ws + 2 * (size_t)E);    // 2E floats
        int* rowA     = (int*)(ws + 4 * (size_t)E);    // N
        int* rowB     = rowA + N;                      // N
        float* dinv   = (float*)(rowB + N);            // N
        float* h1     = dinv + (size_t)N;              // 32N
        float* h2     = h1 + 32 * (size_t)N;           // 16N
        int* gcnt     = (int*)(h2 + 16 * (size_t)N);   // MAXB
        int* gstart   = gcnt + MAXB;                   // MAXB
        int* gcur     = gstart + MAXB;                 // MAXB

        // zero only the bucket counters (2 KB)
        hipMemsetAsync(gcnt, 0, MAXB * sizeof(int), stream);

        bucket_count_kernel<<<1024, BLK, 0, stream>>>(dst, gcnt, E);
        bucket_scan_kernel<<<1, BLK, 0, stream>>>(gcnt, gstart, gcur, B);
        partition_kernel<<<(E + CHUNK - 1) / CHUNK, BLKW, 0, stream>>>(
            src, dst, ew, gcur, packed, E);
        bucket_sort_kernel<<<B, BLKW, 0, stream>>>(packed, gstart, gcnt,
                                                   packed2, rowA, rowB, dinv, N);
        // packed (regionA) dead from here; g1/g2 overlay it.

        gemm1_kernel<<<(N + 7) / 8, BLK, 0, stream>>>(x, W1, dinv, g1, N);
        gather_kernel<32><<<(N + 7) / 8, BLK, 0, stream>>>(packed2, rowA, rowB,
                                                           g1, dinv, b1, h1, N);
        gemm2_kernel<<<(N + 15) / 16, BLK, 0, stream>>>(h1, dinv, W2, g2, N);
        gather_kernel<16><<<(N + 15) / 16, BLK, 0, stream>>>(packed2, rowA, rowB,
                                                             g2, dinv, b2, h2, N);
        final_kernel2<<<(N + BLK - 1) / BLK, BLK, 0, stream>>>(h2, Wout, bout,
                                                               out, N);
    } else {
        // ---------- fallback: proven atomic path ----------
        float* ws   = (float*)d_ws;
        float* deg  = ws;
        float* agg1 = ws + (size_t)N;
        float* agg2 = ws + (size_t)33 * N;
        float* g1   = ws + (size_t)49 * N;
        float* g2   = ws + (size_t)81 * N;

        hipMemsetAsync(ws, 0, (size_t)49 * N * sizeof(float), stream);

        deg_kernel<<<(E + BLK - 1) / BLK, BLK, 0, stream>>>(dst, ew, deg, E);
        dinvf_kernel<<<(N + BLK - 1) / BLK, BLK, 0, stream>>>(deg, N);
        gemm1_kernel<<<(N + 7) / 8, BLK, 0, stream>>>(x, W1, deg, g1, N);
        {
            unsigned total = (unsigned)E * 32u;
            edge_agg_kernel<32><<<(total + BLK - 1) / BLK, BLK, 0, stream>>>(
                src, dst, ew, g1, agg1, E);
        }
        layer2_kernel<<<(N + 15) / 16, BLK, 0, stream>>>(agg1, g1, deg, b1, W2, g2, N);
        {
            unsigned total = (unsigned)E * 16u;
            edge_agg_kernel<16><<<(total + BLK - 1) / BLK, BLK, 0, stream>>>(
                src, dst, ew, g2, agg2, E);
        }
        final_kernel<<<(N + BLK - 1) / BLK, BLK, 0, stream>>>(
            agg2, g2, deg, b2, Wout, bout, out, N);
    }
}